// Round 1
// baseline (5567.076 us; speedup 1.0000x reference)
//
#include <hip/hip_runtime.h>
#include <hip/hip_bf16.h>

// GRU autoencoder: B=256, T=512, C=64, H=512.
// One fused GEMM+GRU-cell kernel per recurrence step (512 enc + 513 dec).
// Decoder pred-feedback folded into recurrent weights (low-rank fold):
//   gi = h @ (Wih@Wout)^T + (Wih@bout + bih)
// Gate column layout (blocks of 64 = 16 h-cols x 4 parts):
//   enc: [r | z | gi_n | gh_n]  (K=576 = [x(64) | h(512)], zero-padded blocks)
//   dec: [r+z merged(Af+Whh) | inn(Af_n) | hn(Whh_n)] (K=512) + 64 Wout cols

#define B_ 256
#define T_ 512
#define C_ 64
#define H_ 512

typedef __attribute__((ext_vector_type(8))) short s16x8;
typedef __attribute__((ext_vector_type(4))) float f32x4;

__device__ __forceinline__ unsigned short f2b(float f) {
    unsigned int u = __float_as_uint(f);
    unsigned int r = (u + 0x7FFFu + ((u >> 16) & 1u)) >> 16;
    return (unsigned short)r;
}

// ---------------- weight prep kernels ----------------

// Encoder: WencT [2048][576] bf16 (n-major, k contiguous), benc [2048]
__global__ __launch_bounds__(256) void prep_enc_k(
    const float* __restrict__ Wih, const float* __restrict__ Whh,
    const float* __restrict__ bih, const float* __restrict__ bhh,
    unsigned short* __restrict__ W, float* __restrict__ bias)
{
    int idx = blockIdx.x * 256 + threadIdx.x;
    if (idx >= 2048 * 576) return;
    int n = idx / 576, k = idx % 576;
    int part = (n >> 4) & 3, jc = n & 15, j16 = n >> 6;
    int j = j16 * 16 + jc;
    float v;
    if (part == 0)      v = (k < 64) ? Wih[j * 64 + k]          : Whh[(size_t)j * 512 + (k - 64)];
    else if (part == 1) v = (k < 64) ? Wih[(512 + j) * 64 + k]  : Whh[(size_t)(512 + j) * 512 + (k - 64)];
    else if (part == 2) v = (k < 64) ? Wih[(1024 + j) * 64 + k] : 0.f;
    else                v = (k < 64) ? 0.f                       : Whh[(size_t)(1024 + j) * 512 + (k - 64)];
    W[(size_t)n * 576 + k] = f2b(v);
    if (k == 0) {
        float b;
        if (part == 0)      b = bih[j] + bhh[j];
        else if (part == 1) b = bih[512 + j] + bhh[512 + j];
        else if (part == 2) b = bih[1024 + j];
        else                b = bhh[1024 + j];
        bias[n] = b;
    }
}

// Decoder: W1 = steady-state weights (with Af=Wih@Wout fold), W0 = step-0 weights.
// blockIdx.x = n in [0,2112); 256 threads each handle k=tid, tid+256.
__global__ __launch_bounds__(256) void prep_dec_k(
    const float* __restrict__ Wih, const float* __restrict__ Whh,
    const float* __restrict__ Wout,
    unsigned short* __restrict__ W1, unsigned short* __restrict__ W0)
{
    int n = blockIdx.x;
    __shared__ float wrow[64];
    bool isout = (n >= 2048);
    int part = 0, j = 0, n3 = 0;
    if (!isout) {
        part = (n >> 4) & 3;
        int jc = n & 15, j16 = n >> 6;
        j = j16 * 16 + jc;
        n3 = (part == 0) ? j : (part == 1) ? (512 + j) : (1024 + j);
    }
    if (threadIdx.x < 64 && !isout && part != 3)
        wrow[threadIdx.x] = Wih[n3 * 64 + threadIdx.x];
    __syncthreads();
    for (int kk = 0; kk < 2; ++kk) {
        int k = kk * 256 + threadIdx.x;
        float v1, v0;
        if (isout) {
            v1 = v0 = Wout[(size_t)(n - 2048) * 512 + k];
        } else if (part == 3) {
            v1 = v0 = Whh[(size_t)(1024 + j) * 512 + k];
        } else {
            float af = 0.f;
            #pragma unroll
            for (int c = 0; c < 64; ++c) af += wrow[c] * Wout[(size_t)c * 512 + k];
            if (part == 2) { v1 = af; v0 = 0.f; }
            else { float wh = Whh[(size_t)n3 * 512 + k]; v1 = af + wh; v0 = wh; }
        }
        W1[(size_t)n * 512 + k] = f2b(v1);
        W0[(size_t)n * 512 + k] = f2b(v0);
    }
}

__global__ __launch_bounds__(256) void prep_dec_bias_k(
    const float* __restrict__ Wih, const float* __restrict__ bih,
    const float* __restrict__ bhh, const float* __restrict__ bout,
    float* __restrict__ b1, float* __restrict__ b0)
{
    int n = blockIdx.x * 256 + threadIdx.x;
    if (n >= 2112) return;
    if (n >= 2048) { b1[n] = bout[n - 2048]; b0[n] = bout[n - 2048]; return; }
    int part = (n >> 4) & 3, jc = n & 15, j16 = n >> 6;
    int j = j16 * 16 + jc;
    float v1, v0;
    if (part == 3) { v1 = v0 = bhh[1024 + j]; }
    else {
        int n3 = (part == 0) ? j : (part == 1) ? (512 + j) : (1024 + j);
        float wib = 0.f;
        #pragma unroll
        for (int c = 0; c < 64; ++c) wib += Wih[n3 * 64 + c] * bout[c];
        if (part == 2) { v1 = bih[1024 + j] + wib; v0 = bih[1024 + j]; }
        else { float base = bih[n3] + bhh[n3]; v1 = base + wib; v0 = base; }
    }
    b1[n] = v1; b0[n] = v0;
}

// ---------------- fused step kernel ----------------
// MODE 0 = encoder (K=576, A=[x_t|h]); MODE 1 = decoder (K=512, A=h).
// Tile: 32 batch rows x 64 gate cols per WG, 4 waves, K-chunk 64.
template <int MODE>
__global__ __launch_bounds__(256) void step_kernel(
    const unsigned short* __restrict__ Wt, const float* __restrict__ bias,
    const float* __restrict__ xin, int t,
    const unsigned short* __restrict__ h16_in, const float* __restrict__ h32_in,
    float* __restrict__ h32_out, unsigned short* __restrict__ h16_out,
    float* __restrict__ pred_out, int by_off)
{
    constexpr int K = (MODE == 0) ? 576 : 512;
    constexpr int NCH = K / 64;
    __shared__ unsigned short Al[32][72];
    __shared__ unsigned short Bl[64][72];
    __shared__ float Ol[32][68];

    const int tid = threadIdx.x;
    const int bx = blockIdx.x, by = blockIdx.y + by_off;
    const int b0 = bx * 32, n0 = by * 64;
    const bool is_pred = (MODE == 1) && (by == 32);

    const int w = tid >> 6, l = tid & 63;
    const int lrow = l & 15, lk = (l >> 4) * 8;
    const int WR = (w >> 1) * 16, WC = (w & 1) * 32;

    f32x4 acc0 = {0.f, 0.f, 0.f, 0.f};
    f32x4 acc1 = {0.f, 0.f, 0.f, 0.f};

    const int arow = tid >> 3, aseg = tid & 7;   // A: 32 rows x 64 k, 16B/thread
    const int brow = tid >> 2, bseg = tid & 3;   // B: 64 rows x 64 k, 2x16B/thread

    for (int kc = 0; kc < NCH; ++kc) {
        const int k0 = kc * 64;
        // ---- stage A ----
        if (MODE == 0 && kc == 0) {
            // pure-x chunk (k 0..63): fp32 -> bf16
            const float* src = xin + (size_t)(b0 + arow) * (T_ * C_) + (size_t)t * C_ + aseg * 8;
            float4 f0 = *(const float4*)src;
            float4 f1 = *(const float4*)(src + 4);
            s16x8 v;
            v[0] = (short)f2b(f0.x); v[1] = (short)f2b(f0.y);
            v[2] = (short)f2b(f0.z); v[3] = (short)f2b(f0.w);
            v[4] = (short)f2b(f1.x); v[5] = (short)f2b(f1.y);
            v[6] = (short)f2b(f1.z); v[7] = (short)f2b(f1.w);
            *(s16x8*)&Al[arow][aseg * 8] = v;
        } else {
            const int hk = ((MODE == 0) ? (k0 - 64) : k0) + aseg * 8;
            *(s16x8*)&Al[arow][aseg * 8] =
                *(const s16x8*)(h16_in + (size_t)(b0 + arow) * H_ + hk);
        }
        // ---- stage B (weights) ----
        #pragma unroll
        for (int hh = 0; hh < 2; ++hh) {
            const int kk = k0 + hh * 32 + bseg * 8;
            *(s16x8*)&Bl[brow][hh * 32 + bseg * 8] =
                *(const s16x8*)(Wt + (size_t)(n0 + brow) * K + kk);
        }
        __syncthreads();
        // ---- MFMA: 2 k-steps of 32 ----
        #pragma unroll
        for (int ks = 0; ks < 2; ++ks) {
            s16x8 af  = *(const s16x8*)&Al[WR + lrow][ks * 32 + lk];
            s16x8 bf0 = *(const s16x8*)&Bl[WC + lrow][ks * 32 + lk];
            s16x8 bf1 = *(const s16x8*)&Bl[WC + 16 + lrow][ks * 32 + lk];
            acc0 = __builtin_amdgcn_mfma_f32_16x16x32_bf16(af, bf0, acc0, 0, 0, 0);
            acc1 = __builtin_amdgcn_mfma_f32_16x16x32_bf16(af, bf1, acc1, 0, 0, 0);
        }
        __syncthreads();
    }

    // ---- write accumulators to LDS (C/D layout: col=l&15, row=4*(l>>4)+r) ----
    #pragma unroll
    for (int r = 0; r < 4; ++r) {
        Ol[WR + 4 * (l >> 4) + r][WC + lrow]      = acc0[r];
        Ol[WR + 4 * (l >> 4) + r][WC + 16 + lrow] = acc1[r];
    }
    __syncthreads();

    if (!is_pred) {
        // GRU cell for 32 rows x 16 h-cols (this block's j16 = by)
        const int jc = tid & 15, r0 = tid >> 4;
        const int j = by * 16 + jc;
        const float b_r = bias[n0 + jc];
        const float b_z = bias[n0 + 16 + jc];
        const float b_i = bias[n0 + 32 + jc];
        const float b_h = bias[n0 + 48 + jc];
        #pragma unroll
        for (int rr = 0; rr < 2; ++rr) {
            const int row = r0 + rr * 16;
            const float gr = Ol[row][jc]      + b_r;
            const float gz = Ol[row][16 + jc] + b_z;
            const float gi = Ol[row][32 + jc] + b_i;
            const float gh = Ol[row][48 + jc] + b_h;
            const float rg = 1.f / (1.f + __expf(-gr));
            const float zg = 1.f / (1.f + __expf(-gz));
            const float ng = tanhf(gi + rg * gh);
            const int bI = b0 + row;
            const float hold = h32_in[(size_t)bI * H_ + j];
            const float hnew = (1.f - zg) * ng + zg * hold;
            h32_out[(size_t)bI * H_ + j] = hnew;
            h16_out[(size_t)bI * H_ + j] = f2b(hnew);
        }
    } else if (pred_out != nullptr) {
        // pred block: 32 rows x 64 cols -> d_out
        #pragma unroll
        for (int q = 0; q < 8; ++q) {
            const int ii = q * 256 + tid;
            const int row = ii >> 6, col = ii & 63;
            pred_out[(size_t)(b0 + row) * (T_ * C_) + col] = Ol[row][col] + bias[2048 + col];
        }
    }
}

// ---------------- host launcher ----------------

extern "C" void kernel_launch(void* const* d_in, const int* in_sizes, int n_in,
                              void* d_out, int out_size, void* d_ws, size_t ws_size,
                              hipStream_t stream) {
    const float* x     = (const float*)d_in[0];
    const float* eWih  = (const float*)d_in[1];
    const float* eWhh  = (const float*)d_in[2];
    const float* ebih  = (const float*)d_in[3];
    const float* ebhh  = (const float*)d_in[4];
    const float* dWih  = (const float*)d_in[5];
    const float* dWhh  = (const float*)d_in[6];
    const float* dbih  = (const float*)d_in[7];
    const float* dbhh  = (const float*)d_in[8];
    const float* Wout  = (const float*)d_in[9];
    const float* bout  = (const float*)d_in[10];

    // workspace carve (256B aligned)
    size_t off = 0;
    auto carve = [&](size_t bytes) -> void* {
        off = (off + 255) & ~(size_t)255;
        void* p = (char*)d_ws + off;
        off += bytes;
        return p;
    };
    unsigned short* WencT  = (unsigned short*)carve((size_t)2048 * 576 * 2);
    unsigned short* WdecT  = (unsigned short*)carve((size_t)2112 * 512 * 2);
    unsigned short* Wdec0T = (unsigned short*)carve((size_t)2112 * 512 * 2);
    float* benc  = (float*)carve(2048 * 4);
    float* bdec  = (float*)carve(2112 * 4);
    float* bdec0 = (float*)carve(2112 * 4);
    float* h32   = (float*)carve((size_t)2 * B_ * H_ * 4);
    unsigned short* h16 = (unsigned short*)carve((size_t)2 * B_ * H_ * 2);

    float* h32b[2] = {h32, h32 + (size_t)B_ * H_};
    unsigned short* h16b[2] = {h16, h16 + (size_t)B_ * H_};

    // zero initial hidden state (buffer 0)
    hipMemsetAsync(h32b[0], 0, (size_t)B_ * H_ * 4, stream);
    hipMemsetAsync(h16b[0], 0, (size_t)B_ * H_ * 2, stream);

    // weight prep
    prep_enc_k<<<(2048 * 576 + 255) / 256, 256, 0, stream>>>(eWih, eWhh, ebih, ebhh, WencT, benc);
    prep_dec_k<<<2112, 256, 0, stream>>>(dWih, dWhh, Wout, WdecT, Wdec0T);
    prep_dec_bias_k<<<9, 256, 0, stream>>>(dWih, dbih, dbhh, bout, bdec, bdec0);

    int p = 0;
    // encoder: 512 steps
    for (int t = 0; t < T_; ++t) {
        step_kernel<0><<<dim3(8, 32), 256, 0, stream>>>(
            WencT, benc, x, t, h16b[p], h32b[p], h32b[p ^ 1], h16b[p ^ 1], nullptr, 0);
        p ^= 1;
    }
    // decoder: 512 steps (step s also emits pred_{s-1})
    for (int s = 0; s < T_; ++s) {
        const unsigned short* Wt = s ? WdecT : Wdec0T;
        const float* bs = s ? bdec : bdec0;
        float* po = s ? ((float*)d_out + (size_t)(s - 1) * C_) : nullptr;
        step_kernel<1><<<dim3(8, 33), 256, 0, stream>>>(
            Wt, bs, nullptr, 0, h16b[p], h32b[p], h32b[p ^ 1], h16b[p ^ 1], po, 0);
        p ^= 1;
    }
    // final pred_{T-1} (pred-only launch: by_off=32 selects the Wout block)
    step_kernel<1><<<dim3(8, 1), 256, 0, stream>>>(
        WdecT, bdec, nullptr, 0, h16b[p], h32b[p], h32b[p ^ 1], h16b[p ^ 1],
        (float*)d_out + (size_t)(T_ - 1) * C_, 32);
}

// Round 3
// 4478.493 us; speedup vs baseline: 1.2431x; 1.2431x over previous
//
#include <hip/hip_runtime.h>
#include <hip/hip_bf16.h>

// GRU autoencoder B=256,T=512,C=64,H=512 — single persistent kernel.
// 8 groups x 32 batch-rows; group = blocks {8k+g} (XCD-local under round-robin).
// Block = 32 rows x 64 gate cols; 4 waves = (K-half kh) x (row-half rh).
// Weights held in VGPRs (36 frags/wave); gates fully in-lane -> in-register cell.
// h16 exchange: relaxed agent-scope atomics (no cache-wide fences).
// Decoder pred feedback folded into weights: gi = h@(Wih@Wout)^T + (Wih@bout+bih).
// R3 fix: pred B-fragment index pfr[i] (R2 had a precedence bug -> pfr[7] for kh=1).

#define B_ 256
#define T_ 512
#define C_ 64
#define H_ 512
#define TC_ 32768   // T_*C_
#define BH_ 131072  // B_*H_

typedef __attribute__((ext_vector_type(8))) short s16x8;
typedef __attribute__((ext_vector_type(4))) float f32x4;

__device__ __forceinline__ unsigned short f2b(float f) {
    unsigned int u = __float_as_uint(f);
    unsigned int r = (u + 0x7FFFu + ((u >> 16) & 1u)) >> 16;
    return (unsigned short)r;
}
__device__ __forceinline__ float sigm(float v) { return 1.f / (1.f + __expf(-v)); }

// ---------------- weight prep kernels (validated in R1) ----------------

__global__ __launch_bounds__(256) void prep_enc_k(
    const float* __restrict__ Wih, const float* __restrict__ Whh,
    const float* __restrict__ bih, const float* __restrict__ bhh,
    unsigned short* __restrict__ W, float* __restrict__ bias)
{
    int idx = blockIdx.x * 256 + threadIdx.x;
    if (idx >= 2048 * 576) return;
    int n = idx / 576, k = idx % 576;
    int part = (n >> 4) & 3, jc = n & 15, j16 = n >> 6;
    int j = j16 * 16 + jc;
    float v;
    if (part == 0)      v = (k < 64) ? Wih[j * 64 + k]          : Whh[(size_t)j * 512 + (k - 64)];
    else if (part == 1) v = (k < 64) ? Wih[(512 + j) * 64 + k]  : Whh[(size_t)(512 + j) * 512 + (k - 64)];
    else if (part == 2) v = (k < 64) ? Wih[(1024 + j) * 64 + k] : 0.f;
    else                v = (k < 64) ? 0.f                       : Whh[(size_t)(1024 + j) * 512 + (k - 64)];
    W[(size_t)n * 576 + k] = f2b(v);
    if (k == 0) {
        float b;
        if (part == 0)      b = bih[j] + bhh[j];
        else if (part == 1) b = bih[512 + j] + bhh[512 + j];
        else if (part == 2) b = bih[1024 + j];
        else                b = bhh[1024 + j];
        bias[n] = b;
    }
}

__global__ __launch_bounds__(256) void prep_dec_k(
    const float* __restrict__ Wih, const float* __restrict__ Whh,
    const float* __restrict__ Wout,
    unsigned short* __restrict__ W1, unsigned short* __restrict__ W0)
{
    int n = blockIdx.x;
    __shared__ float wrow[64];
    bool isout = (n >= 2048);
    int part = 0, j = 0, n3 = 0;
    if (!isout) {
        part = (n >> 4) & 3;
        int jc = n & 15, j16 = n >> 6;
        j = j16 * 16 + jc;
        n3 = (part == 0) ? j : (part == 1) ? (512 + j) : (1024 + j);
    }
    if (threadIdx.x < 64 && !isout && part != 3)
        wrow[threadIdx.x] = Wih[n3 * 64 + threadIdx.x];
    __syncthreads();
    for (int kk = 0; kk < 2; ++kk) {
        int k = kk * 256 + threadIdx.x;
        float v1, v0;
        if (isout) {
            v1 = v0 = Wout[(size_t)(n - 2048) * 512 + k];
        } else if (part == 3) {
            v1 = v0 = Whh[(size_t)(1024 + j) * 512 + k];
        } else {
            float af = 0.f;
            #pragma unroll
            for (int c = 0; c < 64; ++c) af += wrow[c] * Wout[(size_t)c * 512 + k];
            if (part == 2) { v1 = af; v0 = 0.f; }
            else { float wh = Whh[(size_t)n3 * 512 + k]; v1 = af + wh; v0 = wh; }
        }
        W1[(size_t)n * 512 + k] = f2b(v1);
        W0[(size_t)n * 512 + k] = f2b(v0);
    }
}

__global__ __launch_bounds__(256) void prep_dec_bias_k(
    const float* __restrict__ Wih, const float* __restrict__ bih,
    const float* __restrict__ bhh, const float* __restrict__ bout,
    float* __restrict__ b1, float* __restrict__ b0)
{
    int n = blockIdx.x * 256 + threadIdx.x;
    if (n >= 2112) return;
    if (n >= 2048) { b1[n] = bout[n - 2048]; b0[n] = bout[n - 2048]; return; }
    int part = (n >> 4) & 3, jc = n & 15, j16 = n >> 6;
    int j = j16 * 16 + jc;
    float v1, v0;
    if (part == 3) { v1 = v0 = bhh[1024 + j]; }
    else {
        int n3 = (part == 0) ? j : (part == 1) ? (512 + j) : (1024 + j);
        float wib = 0.f;
        #pragma unroll
        for (int c = 0; c < 64; ++c) wib += Wih[n3 * 64 + c] * bout[c];
        if (part == 2) { v1 = bih[1024 + j] + wib; v0 = bih[1024 + j]; }
        else { float base = bih[n3] + bhh[n3]; v1 = base + wib; v0 = base; }
    }
    b1[n] = v1; b0[n] = v0;
}

// ---------------- persistent recurrence kernel ----------------

template<int NK, bool PRED>
__device__ __forceinline__ void do_step(
    const unsigned short* __restrict__ hin, unsigned short* __restrict__ hout,
    const s16x8 (&bfr)[36], const s16x8 (&pfr)[8], const float4 (&xf)[2][2],
    const float* bR, float bp, float (&h32)[4],
    float* __restrict__ out, int tout,
    int r0, int j, int kh, int rh, int lane, bool duty,
    float (*Ored)[64][28], unsigned short (*Hst)[16][20])
{
    constexpr int HK = NK / 2;
    const int jc = lane & 15, kq = lane >> 4;
    const int ks0 = kh * HK;
    const unsigned short* hrow = hin + (size_t)(r0 + rh * 16 + jc) * H_;

    s16x8 af[HK];
    if (NK == 18 && kh == 0) {
        #pragma unroll
        for (int i2 = 0; i2 < 2; ++i2) {
            s16x8 v;
            v[0] = (short)f2b(xf[i2][0].x); v[1] = (short)f2b(xf[i2][0].y);
            v[2] = (short)f2b(xf[i2][0].z); v[3] = (short)f2b(xf[i2][0].w);
            v[4] = (short)f2b(xf[i2][1].x); v[5] = (short)f2b(xf[i2][1].y);
            v[6] = (short)f2b(xf[i2][1].z); v[7] = (short)f2b(xf[i2][1].w);
            af[i2] = v;
        }
    }
    #pragma unroll
    for (int i = 0; i < HK; ++i) {
        const int gks = ks0 + i;
        const bool isx = (NK == 18) && (gks < 2);
        if (!isx) {
            const int hk = ((NK == 18) ? (gks - 2) : gks) * 32 + kq * 8;
            const unsigned long long* hp = (const unsigned long long*)(hrow + hk);
            union { unsigned long long u[2]; s16x8 v; } cv;
            cv.u[0] = __hip_atomic_load(hp,     __ATOMIC_RELAXED, __HIP_MEMORY_SCOPE_AGENT);
            cv.u[1] = __hip_atomic_load(hp + 1, __ATOMIC_RELAXED, __HIP_MEMORY_SCOPE_AGENT);
            af[i] = cv.v;
        }
    }

    f32x4 acc[4] = {{0,0,0,0},{0,0,0,0},{0,0,0,0},{0,0,0,0}};
    f32x4 pacc = {0,0,0,0};
    #pragma unroll
    for (int i = 0; i < HK; ++i) {
        #pragma unroll
        for (int q = 0; q < 4; ++q)
            acc[q] = __builtin_amdgcn_mfma_f32_16x16x32_bf16(af[i], bfr[i * 4 + q], acc[q], 0, 0, 0);
        if (PRED && duty)
            pacc = __builtin_amdgcn_mfma_f32_16x16x32_bf16(af[i], pfr[i], pacc, 0, 0, 0);
    }

    if (kh == 1) {
        #pragma unroll
        for (int q = 0; q < 4; ++q) *(f32x4*)&Ored[rh][lane][q * 4] = acc[q];
        if (PRED && duty) *(f32x4*)&Ored[rh][lane][16] = pacc;
    }
    asm volatile("s_waitcnt lgkmcnt(0)" ::: "memory");
    __builtin_amdgcn_s_barrier();
    __builtin_amdgcn_sched_barrier(0);

    if (kh == 0) {
        #pragma unroll
        for (int q = 0; q < 4; ++q) {
            f32x4 o = *(const f32x4*)&Ored[rh][lane][q * 4];
            acc[q] = acc[q] + o;
        }
        if (PRED && duty) {
            f32x4 o = *(const f32x4*)&Ored[rh][lane][16];
            pacc = pacc + o;
        }
        float hn[4];
        #pragma unroll
        for (int r = 0; r < 4; ++r) {
            float gr = acc[0][r] + bR[0];
            float gz = acc[1][r] + bR[1];
            float gi = acc[2][r] + bR[2];
            float gh = acc[3][r] + bR[3];
            float rg = sigm(gr), zg = sigm(gz);
            float ng = tanhf(gi + rg * gh);
            hn[r] = (1.f - zg) * ng + zg * h32[r];
            h32[r] = hn[r];
        }
        #pragma unroll
        for (int r = 0; r < 4; ++r) Hst[rh][kq * 4 + r][jc] = f2b(hn[r]);
        asm volatile("s_waitcnt lgkmcnt(0)" ::: "memory");
        __builtin_amdgcn_sched_barrier(0);
        const int srow = kq * 4 + (jc >> 2), scol = 4 * (jc & 3);
        unsigned long long hv = *(const unsigned long long*)&Hst[rh][srow][scol];
        __hip_atomic_store((unsigned long long*)(hout + (size_t)(r0 + rh * 16 + srow) * H_ + j * 16 + scol),
                           hv, __ATOMIC_RELAXED, __HIP_MEMORY_SCOPE_AGENT);
        if (PRED && duty) {
            #pragma unroll
            for (int r = 0; r < 4; ++r)
                out[(size_t)(r0 + rh * 16 + kq * 4 + r) * TC_ + (size_t)tout * C_ + j * 16 + jc] = pacc[r] + bp;
        }
    }
}

__global__ __launch_bounds__(256, 1) void gru_persist(
    const unsigned short* __restrict__ WencT,
    const unsigned short* __restrict__ WdecT,
    const unsigned short* __restrict__ Wdec0T,
    const float* __restrict__ benc, const float* __restrict__ bdec, const float* __restrict__ bdec0,
    const float* __restrict__ x,
    unsigned short* __restrict__ h16,
    float* __restrict__ out,
    unsigned int* __restrict__ bar)
{
    __shared__ __align__(16) float Ored[2][64][28];
    __shared__ __align__(16) unsigned short Hst[2][16][20];

    const int bid = blockIdx.x;
    const int g = bid & 7, j = bid >> 3;
    const int tid = threadIdx.x;
    const int w = tid >> 6, lane = tid & 63;
    const int kh = w & 1, rh = w >> 1;
    const int jc = lane & 15, kq = lane >> 4;
    const int r0 = g * 32;
    const bool duty = (j < 4);

    float be[4], bd[4], bd0[4];
    #pragma unroll
    for (int q = 0; q < 4; ++q) {
        be[q]  = benc[j * 64 + q * 16 + jc];
        bd[q]  = bdec[j * 64 + q * 16 + jc];
        bd0[q] = bdec0[j * 64 + q * 16 + jc];
    }
    const float bp = duty ? bdec[2048 + j * 16 + jc] : 0.f;

    // encoder weight fragments -> registers (once)
    s16x8 bfr[36];
    #pragma unroll
    for (int i = 0; i < 9; ++i) {
        const int gks = kh * 9 + i;
        #pragma unroll
        for (int q = 0; q < 4; ++q)
            bfr[i * 4 + q] = *(const s16x8*)(WencT + (size_t)(j * 64 + q * 16 + jc) * 576 + gks * 32 + kq * 8);
    }
    s16x8 pfr[8];
    #pragma unroll
    for (int i = 0; i < 8; ++i) pfr[i] = s16x8{0,0,0,0,0,0,0,0};

    float h32[4] = {0.f, 0.f, 0.f, 0.f};
    unsigned int* mybar = bar + g * 64;
    int parity = 0;
    float4 xf[2][2];

    for (int step = 0; step < 1024; ++step) {
        const bool enc = step < 512;
        // early x issue (independent of barrier; latency hides under spin)
        if (enc && kh == 0) {
            const float* xp = x + (size_t)(r0 + rh * 16 + jc) * TC_ + (size_t)step * C_ + kq * 8;
            #pragma unroll
            for (int i2 = 0; i2 < 2; ++i2) {
                xf[i2][0] = *(const float4*)(xp + i2 * 32);
                xf[i2][1] = *(const float4*)(xp + i2 * 32 + 4);
            }
        }
        // phase-change weight reloads (overlap the barrier wait)
        if (step == 512) {
            #pragma unroll
            for (int i = 0; i < 8; ++i) {
                const int gks = kh * 8 + i;
                #pragma unroll
                for (int q = 0; q < 4; ++q)
                    bfr[i * 4 + q] = *(const s16x8*)(Wdec0T + (size_t)(j * 64 + q * 16 + jc) * 512 + gks * 32 + kq * 8);
                if (duty)
                    pfr[i] = *(const s16x8*)(WdecT + (size_t)(2048 + j * 16 + jc) * 512 + gks * 32 + kq * 8);
            }
        } else if (step == 513) {
            #pragma unroll
            for (int i = 0; i < 8; ++i) {
                const int gks = kh * 8 + i;
                #pragma unroll
                for (int q = 0; q < 4; ++q)
                    bfr[i * 4 + q] = *(const s16x8*)(WdecT + (size_t)(j * 64 + q * 16 + jc) * 512 + gks * 32 + kq * 8);
            }
        }
        // group barrier wait
        if (step > 0) {
            if (tid == 0) {
                const unsigned int tgt = 32u * (unsigned int)step;
                while (__hip_atomic_load(mybar, __ATOMIC_RELAXED, __HIP_MEMORY_SCOPE_AGENT) < tgt)
                    __builtin_amdgcn_s_sleep(1);
            }
            __builtin_amdgcn_s_barrier();
            __builtin_amdgcn_sched_barrier(0);
        }
        const unsigned short* hin = h16 + (size_t)parity * BH_;
        unsigned short* hout = h16 + (size_t)(parity ^ 1) * BH_;

        if (enc)
            do_step<18, false>(hin, hout, bfr, pfr, xf, be,  bp, h32, out, 0,          r0, j, kh, rh, lane, duty, Ored, Hst);
        else if (step == 512)
            do_step<16, false>(hin, hout, bfr, pfr, xf, bd0, bp, h32, out, 0,          r0, j, kh, rh, lane, duty, Ored, Hst);
        else
            do_step<16, true >(hin, hout, bfr, pfr, xf, bd,  bp, h32, out, step - 513, r0, j, kh, rh, lane, duty, Ored, Hst);

        asm volatile("s_waitcnt vmcnt(0)" ::: "memory");
        __builtin_amdgcn_s_barrier();
        __builtin_amdgcn_sched_barrier(0);
        if (tid == 0)
            __hip_atomic_fetch_add(mybar, 1u, __ATOMIC_RELAXED, __HIP_MEMORY_SCOPE_AGENT);
        parity ^= 1;
    }

    // final pred_{511} from h_512 (duty blocks only; uniform per block)
    if (duty) {
        if (tid == 0) {
            while (__hip_atomic_load(mybar, __ATOMIC_RELAXED, __HIP_MEMORY_SCOPE_AGENT) < 32u * 1024u)
                __builtin_amdgcn_s_sleep(1);
        }
        __builtin_amdgcn_s_barrier();
        __builtin_amdgcn_sched_barrier(0);
        const unsigned short* hin = h16 + (size_t)parity * BH_;
        const unsigned short* hrow = hin + (size_t)(r0 + rh * 16 + jc) * H_;
        f32x4 pacc = {0, 0, 0, 0};
        #pragma unroll
        for (int i = 0; i < 8; ++i) {
            const int gks = kh * 8 + i;
            const int hk = gks * 32 + kq * 8;
            const unsigned long long* hp = (const unsigned long long*)(hrow + hk);
            union { unsigned long long u[2]; s16x8 v; } cv;
            cv.u[0] = __hip_atomic_load(hp,     __ATOMIC_RELAXED, __HIP_MEMORY_SCOPE_AGENT);
            cv.u[1] = __hip_atomic_load(hp + 1, __ATOMIC_RELAXED, __HIP_MEMORY_SCOPE_AGENT);
            pacc = __builtin_amdgcn_mfma_f32_16x16x32_bf16(cv.v, pfr[i], pacc, 0, 0, 0);
        }
        if (kh == 1) *(f32x4*)&Ored[rh][lane][16] = pacc;
        asm volatile("s_waitcnt lgkmcnt(0)" ::: "memory");
        __builtin_amdgcn_s_barrier();
        __builtin_amdgcn_sched_barrier(0);
        if (kh == 0) {
            f32x4 o = *(const f32x4*)&Ored[rh][lane][16];
            pacc = pacc + o;
            #pragma unroll
            for (int r = 0; r < 4; ++r)
                out[(size_t)(r0 + rh * 16 + kq * 4 + r) * TC_ + (size_t)511 * C_ + j * 16 + jc] = pacc[r] + bp;
        }
    }
}

// ---------------- host launcher ----------------

extern "C" void kernel_launch(void* const* d_in, const int* in_sizes, int n_in,
                              void* d_out, int out_size, void* d_ws, size_t ws_size,
                              hipStream_t stream) {
    const float* x    = (const float*)d_in[0];
    const float* eWih = (const float*)d_in[1];
    const float* eWhh = (const float*)d_in[2];
    const float* ebih = (const float*)d_in[3];
    const float* ebhh = (const float*)d_in[4];
    const float* dWih = (const float*)d_in[5];
    const float* dWhh = (const float*)d_in[6];
    const float* dbih = (const float*)d_in[7];
    const float* dbhh = (const float*)d_in[8];
    const float* Wout = (const float*)d_in[9];
    const float* bout = (const float*)d_in[10];

    size_t off = 0;
    auto carve = [&](size_t bytes) -> void* {
        off = (off + 255) & ~(size_t)255;
        void* p = (char*)d_ws + off;
        off += bytes;
        return p;
    };
    unsigned short* WencT  = (unsigned short*)carve((size_t)2048 * 576 * 2);
    unsigned short* WdecT  = (unsigned short*)carve((size_t)2112 * 512 * 2);
    unsigned short* Wdec0T = (unsigned short*)carve((size_t)2112 * 512 * 2);
    float* benc  = (float*)carve(2048 * 4);
    float* bdec  = (float*)carve(2112 * 4);
    float* bdec0 = (float*)carve(2112 * 4);
    unsigned short* h16 = (unsigned short*)carve((size_t)2 * BH_ * 2);
    unsigned int* bar   = (unsigned int*)carve(8 * 64 * 4);

    hipMemsetAsync(h16, 0, (size_t)2 * BH_ * 2, stream);
    hipMemsetAsync(bar, 0, 8 * 64 * 4, stream);

    prep_enc_k<<<(2048 * 576 + 255) / 256, 256, 0, stream>>>(eWih, eWhh, ebih, ebhh, WencT, benc);
    prep_dec_k<<<2112, 256, 0, stream>>>(dWih, dWhh, Wout, WdecT, Wdec0T);
    prep_dec_bias_k<<<9, 256, 0, stream>>>(dWih, dbih, dbhh, bout, bdec, bdec0);

    gru_persist<<<256, 256, 0, stream>>>(WencT, WdecT, Wdec0T, benc, bdec, bdec0,
                                         x, h16, (float*)d_out, bar);
}